// Round 1
// baseline (411.939 us; speedup 1.0000x reference)
//
#include <hip/hip_runtime.h>

// Problem constants (match reference)
#define NEQ_   4096
#define XDIM_  6144
#define BROWS  512
#define EEDGES 32768

typedef __bf16 bf16x8 __attribute__((ext_vector_type(8)));
typedef float  f32x4  __attribute__((ext_vector_type(4)));

__device__ __forceinline__ unsigned short f2bf(float f) {
    union { float f; unsigned u; } v; v.f = f;
    unsigned r = v.u + 0x7FFFu + ((v.u >> 16) & 1u);   // RNE
    return (unsigned short)(r >> 16);
}

// ---- GCN prologue (tiny: only nodes < 4096 are touched by edges) ----

__global__ void gcn_init(int* __restrict__ c1, float* __restrict__ S) {
    int i = blockIdx.x * 256 + threadIdx.x;
    if (i < NEQ_) { c1[i] = 0; S[i] = 0.f; }
}

__global__ void gcn_hist(const int* __restrict__ dst, int* __restrict__ c1) {
    int e = blockIdx.x * 256 + threadIdx.x;
    if (e < EEDGES) atomicAdd(&c1[dst[e]], 1);
}

__global__ void gcn_dinv(const int* __restrict__ c1, float* __restrict__ dinv) {
    int i = blockIdx.x * 256 + threadIdx.x;
    if (i < NEQ_) dinv[i] = rsqrtf(512.f * (float)c1[i] + 1.f);
}

__global__ void gcn_scatter(const int* __restrict__ src, const int* __restrict__ dst,
                            const float* __restrict__ x, const float* __restrict__ dinv,
                            float* __restrict__ S) {
    int e = blockIdx.x * 256 + threadIdx.x;
    if (e < EEDGES) {
        int s = src[e], d = dst[e];
        // xf[s] = x_d[b = s&511, col = s>>9]
        float xf = x[(size_t)(s & 511) * XDIM_ + (s >> 9)];
        atomicAdd(&S[d], dinv[s] * xf);
    }
}

// z[b,i] (bf16):
//   i <  8    : relu(w*(512*dinv[n]*S[n] + xf[n]/deg[n]) + b0), n = i*512+b
//   8<=i<4096 : relu(w*x + b0)          (self-loop only: deg=1)
//   i >= 4096 : x (x_g passthrough, no relu before W1)
__global__ void build_z(const float* __restrict__ x, const int* __restrict__ c1,
                        const float* __restrict__ dinv, const float* __restrict__ S,
                        const float* __restrict__ gw, const float* __restrict__ gb,
                        unsigned short* __restrict__ z) {
    int i = blockIdx.x * 256 + threadIdx.x;  // 0..6143
    int b = blockIdx.y;                      // 0..511
    float xv = x[(size_t)b * XDIM_ + i];
    float v;
    if (i >= NEQ_) {
        v = xv;
    } else {
        float w00 = gw[0], b0 = gb[0];
        if (i >= 8) {
            v = fmaxf(w00 * xv + b0, 0.f);
        } else {
            int n = i * 512 + b;
            float deg = 512.f * (float)c1[n] + 1.f;
            float outv = w00 * (512.f * dinv[n] * S[n] + xv / deg);
            v = fmaxf(outv + b0, 0.f);
        }
    }
    z[(size_t)b * XDIM_ + i] = f2bf(v);
}

// ---- bf16 MFMA GEMM: C[M,N] = A[M,K](bf16) * Bw[K,N](f32, cvt on load) + bias ----
// 64x64 tile, BK=32, 256 threads = 4 waves, each wave a 32x32 quadrant (2x2 MFMA 16x16x32).

constexpr int BM = 64, BN = 64, BK = 32, LDT = 40;  // LDT: +8 bf16 pad (16B) per row

template<bool RELU, bool OUTBF16>
__global__ __launch_bounds__(256)
void gemm_bf16(const unsigned short* __restrict__ A, const float* __restrict__ Bw,
               const float* __restrict__ bias, void* __restrict__ Cv,
               int N, int K)
{
    __shared__ unsigned short As[BM * LDT];   // As[m][k]
    __shared__ unsigned short Bs[BN * LDT];   // Bs[n][k]  (transposed during staging)
    const int tid  = threadIdx.x;
    const int lane = tid & 63;
    const int wave = tid >> 6;
    const int m0 = blockIdx.x * BM, n0 = blockIdx.y * BN;
    const int wm = (wave >> 1) * 32, wn = (wave & 1) * 32;

    // A staging: 64 rows x 32 cols bf16; 4 threads/row, 16B each
    const int ar = tid >> 2;
    const int ac = (tid & 3) * 8;
    // B staging: thread owns (n = tid&63, k = (tid>>6)*8 .. +7); gathers 8 f32 rows,
    // converts, writes one ds_write_b128 to Bs[n][k] — conflict-free with LDT=40.
    const int bcol = tid & 63;
    const int bkg  = (tid >> 6) * 8;

    const int fr = lane & 15;          // fragment row/col index
    const int fk = (lane >> 4) * 8;    // fragment k offset

    f32x4 acc[2][2] = {};

    for (int k0 = 0; k0 < K; k0 += BK) {
        uint4 av = *(const uint4*)(A + (size_t)(m0 + ar) * K + k0 + ac);
        *(uint4*)(&As[ar * LDT + ac]) = av;

        union { unsigned short h[8]; uint4 u; } cv;
        #pragma unroll
        for (int j = 0; j < 8; ++j) {
            float f = Bw[(size_t)(k0 + bkg + j) * N + n0 + bcol];
            cv.h[j] = f2bf(f);
        }
        *(uint4*)(&Bs[bcol * LDT + bkg]) = cv.u;

        __syncthreads();

        bf16x8 afrag[2], bfrag[2];
        #pragma unroll
        for (int mt = 0; mt < 2; ++mt)
            afrag[mt] = *(const bf16x8*)(&As[(wm + mt * 16 + fr) * LDT + fk]);
        #pragma unroll
        for (int nt = 0; nt < 2; ++nt)
            bfrag[nt] = *(const bf16x8*)(&Bs[(wn + nt * 16 + fr) * LDT + fk]);
        #pragma unroll
        for (int mt = 0; mt < 2; ++mt)
            #pragma unroll
            for (int nt = 0; nt < 2; ++nt)
                acc[mt][nt] = __builtin_amdgcn_mfma_f32_16x16x32_bf16(
                    afrag[mt], bfrag[nt], acc[mt][nt], 0, 0, 0);

        __syncthreads();
    }

    // C/D layout (m89-verified): col = lane&15, row = (lane>>4)*4 + reg
    const int col = lane & 15;
    const int qr  = (lane >> 4) * 4;
    #pragma unroll
    for (int mt = 0; mt < 2; ++mt)
    #pragma unroll
    for (int nt = 0; nt < 2; ++nt)
    #pragma unroll
    for (int r = 0; r < 4; ++r) {
        int gm = m0 + wm + mt * 16 + qr + r;
        int gn = n0 + wn + nt * 16 + col;
        float v = acc[mt][nt][r] + bias[gn];
        if (RELU) v = fmaxf(v, 0.f);
        if (OUTBF16) ((unsigned short*)Cv)[(size_t)gm * N + gn] = f2bf(v);
        else         ((float*)Cv)[(size_t)gm * N + gn] = v;
    }
}

extern "C" void kernel_launch(void* const* d_in, const int* in_sizes, int n_in,
                              void* d_out, int out_size, void* d_ws, size_t ws_size,
                              hipStream_t stream)
{
    const float* x  = (const float*)d_in[0];
    const int*   ei = (const int*)d_in[1];     // [2, E]: src = ei, dst = ei+E
    const float* gw = (const float*)d_in[2];
    const float* gb = (const float*)d_in[3];
    const float* W1 = (const float*)d_in[4];
    const float* b1 = (const float*)d_in[5];
    const float* W2 = (const float*)d_in[6];
    const float* b2 = (const float*)d_in[7];
    const float* W3 = (const float*)d_in[8];
    const float* b3 = (const float*)d_in[9];
    float* out = (float*)d_out;

    char* ws = (char*)d_ws;
    unsigned short* z  = (unsigned short*)(ws);              // 512*6144 bf16 = 6291456 B
    unsigned short* z1 = (unsigned short*)(ws + 6291456);    // 512*2048 bf16 = 2097152 B
    unsigned short* z2 = (unsigned short*)(ws + 8388608);    // 512*2048 bf16
    int*   c1   = (int*)  (ws + 10485760);                   // 4096 int
    float* S    = (float*)(ws + 10502144);                   // 4096 f32
    float* dinv = (float*)(ws + 10518528);                   // 4096 f32

    hipLaunchKernelGGL(gcn_init,    dim3(16),      dim3(256), 0, stream, c1, S);
    hipLaunchKernelGGL(gcn_hist,    dim3(128),     dim3(256), 0, stream, ei + EEDGES, c1);
    hipLaunchKernelGGL(gcn_dinv,    dim3(16),      dim3(256), 0, stream, c1, dinv);
    hipLaunchKernelGGL(gcn_scatter, dim3(128),     dim3(256), 0, stream, ei, ei + EEDGES, x, dinv, S);
    hipLaunchKernelGGL(build_z,     dim3(24, 512), dim3(256), 0, stream, x, c1, dinv, S, gw, gb, z);

    // z  [512,6144] @ W1[6144,2048] + b1, relu -> z1 (bf16)
    hipLaunchKernelGGL((gemm_bf16<true,  true >), dim3(8, 32), dim3(256), 0, stream, z,  W1, b1, (void*)z1, 2048, 6144);
    // z1 [512,2048] @ W2[2048,2048] + b2, relu -> z2 (bf16)
    hipLaunchKernelGGL((gemm_bf16<true,  true >), dim3(8, 32), dim3(256), 0, stream, z1, W2, b2, (void*)z2, 2048, 2048);
    // z2 [512,2048] @ W3[2048,4096] + b3 -> out (f32)
    hipLaunchKernelGGL((gemm_bf16<false, false>), dim3(8, 64), dim3(256), 0, stream, z2, W3, b3, (void*)out, 4096, 2048);
}

// Round 2
// 273.799 us; speedup vs baseline: 1.5045x; 1.5045x over previous
//
#include <hip/hip_runtime.h>

#define NEQ_   4096
#define XDIM_  6144
#define EEDGES 32768

typedef __bf16 bf16x8 __attribute__((ext_vector_type(8)));
typedef float  f32x4  __attribute__((ext_vector_type(4)));

__device__ __forceinline__ unsigned short f2bf(float f) {
    union { float f; unsigned u; } v; v.f = f;
    unsigned r = v.u + 0x7FFFu + ((v.u >> 16) & 1u);   // RNE
    return (unsigned short)(r >> 16);
}

__device__ __forceinline__ void gll16(const void* g, void* l) {
    __builtin_amdgcn_global_load_lds(
        (const __attribute__((address_space(1))) unsigned int*)g,
        (__attribute__((address_space(3))) unsigned int*)l, 16, 0, 0);
}

// ---- GCN prologue (validated round 1) ----

__global__ void gcn_init(int* __restrict__ c1, float* __restrict__ S) {
    int i = blockIdx.x * 256 + threadIdx.x;
    if (i < NEQ_) { c1[i] = 0; S[i] = 0.f; }
}

__global__ void gcn_hist(const int* __restrict__ dst, int* __restrict__ c1) {
    int e = blockIdx.x * 256 + threadIdx.x;
    if (e < EEDGES) atomicAdd(&c1[dst[e]], 1);
}

__global__ void gcn_dinv(const int* __restrict__ c1, float* __restrict__ dinv) {
    int i = blockIdx.x * 256 + threadIdx.x;
    if (i < NEQ_) dinv[i] = rsqrtf(512.f * (float)c1[i] + 1.f);
}

__global__ void gcn_scatter(const int* __restrict__ src, const int* __restrict__ dst,
                            const float* __restrict__ x, const float* __restrict__ dinv,
                            float* __restrict__ S) {
    int e = blockIdx.x * 256 + threadIdx.x;
    if (e < EEDGES) {
        int s = src[e], d = dst[e];
        float xf = x[(size_t)(s & 511) * XDIM_ + (s >> 9)];
        atomicAdd(&S[d], dinv[s] * xf);
    }
}

__global__ void build_z(const float* __restrict__ x, const int* __restrict__ c1,
                        const float* __restrict__ dinv, const float* __restrict__ S,
                        const float* __restrict__ gw, const float* __restrict__ gb,
                        unsigned short* __restrict__ z) {
    int i = blockIdx.x * 256 + threadIdx.x;  // 0..6143
    int b = blockIdx.y;                      // 0..511
    float xv = x[(size_t)b * XDIM_ + i];
    float v;
    if (i >= NEQ_) {
        v = xv;
    } else {
        float w00 = gw[0], b0 = gb[0];
        if (i >= 8) {
            v = fmaxf(w00 * xv + b0, 0.f);
        } else {
            int n = i * 512 + b;
            float deg = 512.f * (float)c1[n] + 1.f;
            float outv = w00 * (512.f * dinv[n] * S[n] + xv / deg);
            v = fmaxf(outv + b0, 0.f);
        }
    }
    z[(size_t)b * XDIM_ + i] = f2bf(v);
}

// ---- weight transpose+convert: W[K][N] f32 -> Wt[N][K] bf16 ----
// grid (N/64, K/32), 256 thr. Each j-step reads a coalesced 64-wide row segment.
__global__ __launch_bounds__(256)
void tcvt(const float* __restrict__ W, unsigned short* __restrict__ Wt, int K, int N) {
    int n  = blockIdx.x * 64 + (threadIdx.x & 63);
    int kb = (blockIdx.y * 4 + (threadIdx.x >> 6)) * 8;
    union { unsigned short h[8]; uint4 u; } cv;
    #pragma unroll
    for (int j = 0; j < 8; ++j) cv.h[j] = f2bf(W[(size_t)(kb + j) * N + n]);
    *(uint4*)(Wt + (size_t)n * K + kb) = cv.u;
}

// ---- 128x128 MFMA GEMM (m97 structure), split-K partials to P[S][M][N] f32 ----
__global__ __launch_bounds__(256)
void gemm128(const unsigned short* __restrict__ A,   // [M][K] bf16
             const unsigned short* __restrict__ Bt,  // [N][K] bf16
             float* __restrict__ P,                  // [S][M][N] f32
             int M, int N, int K, int kChunk)
{
    __shared__ unsigned short As[128 * 32];
    __shared__ unsigned short Bs[128 * 32];
    const int tid = threadIdx.x, lane = tid & 63, wave = tid >> 6;
    const int m0 = blockIdx.x * 128, n0 = blockIdx.y * 128;
    const int wm = (wave >> 1) * 64, wn = (wave & 1) * 64;
    const int fr = lane & 15, fko = (lane >> 4) * 8;
    const int k0 = blockIdx.z * kChunk, k1 = k0 + kChunk;

    // staging: chunk c = r*256+tid; row = c>>2, col = (c&3)*8 elems; lds off = c*16 B
    const int srow = tid >> 2;
    const int scol = (tid & 3) * 8;
    const size_t aoff0 = (size_t)(m0 + srow) * K + scol;
    const size_t aoff1 = (size_t)(m0 + srow + 64) * K + scol;
    const size_t boff0 = (size_t)(n0 + srow) * K + scol;
    const size_t boff1 = (size_t)(n0 + srow + 64) * K + scol;
    unsigned short* asl0 = &As[srow * 32 + scol];
    unsigned short* asl1 = &As[(srow + 64) * 32 + scol];
    unsigned short* bsl0 = &Bs[srow * 32 + scol];
    unsigned short* bsl1 = &Bs[(srow + 64) * 32 + scol];

    f32x4 acc[4][4] = {};

    for (int kk = k0; kk < k1; kk += 32) {
        gll16(A + aoff0 + kk, asl0);
        gll16(A + aoff1 + kk, asl1);
        gll16(Bt + boff0 + kk, bsl0);
        gll16(Bt + boff1 + kk, bsl1);
        __syncthreads();

        bf16x8 af[4], bf[4];
        #pragma unroll
        for (int t = 0; t < 4; ++t) {
            af[t] = *(const bf16x8*)(&As[(wm + t * 16 + fr) * 32 + fko]);
            bf[t] = *(const bf16x8*)(&Bs[(wn + t * 16 + fr) * 32 + fko]);
        }
        #pragma unroll
        for (int mt = 0; mt < 4; ++mt)
            #pragma unroll
            for (int nt = 0; nt < 4; ++nt)
                acc[mt][nt] = __builtin_amdgcn_mfma_f32_16x16x32_bf16(
                    af[mt], bf[nt], acc[mt][nt], 0, 0, 0);

        __syncthreads();
    }

    float* Pp = P + (size_t)blockIdx.z * M * N;
    const int col = lane & 15, qr = (lane >> 4) * 4;
    #pragma unroll
    for (int mt = 0; mt < 4; ++mt)
    #pragma unroll
    for (int nt = 0; nt < 4; ++nt) {
        int gm = m0 + wm + mt * 16 + qr;
        int gn = n0 + wn + nt * 16 + col;
        #pragma unroll
        for (int r = 0; r < 4; ++r)
            Pp[(size_t)(gm + r) * N + gn] = acc[mt][nt][r];
    }
}

// ---- split-K reduce + bias (+relu) epilogue ----
template<bool RELU, bool OUTBF16>
__global__ __launch_bounds__(256)
void reduce_ep(const float* __restrict__ P, const float* __restrict__ bias,
               void* __restrict__ Out, int MN, int N, int S)
{
    int e = (blockIdx.x * 256 + threadIdx.x) * 4;
    if (e >= MN) return;
    f32x4 v = *(const f32x4*)(P + e);
    for (int s = 1; s < S; ++s) v += *(const f32x4*)(P + (size_t)s * MN + e);
    int nb = e % N;
    f32x4 bv = *(const f32x4*)(bias + nb);
    v += bv;
    if (RELU) {
        #pragma unroll
        for (int j = 0; j < 4; ++j) v[j] = fmaxf(v[j], 0.f);
    }
    if (OUTBF16) {
        union { unsigned short h[4]; uint2 u; } cv;
        #pragma unroll
        for (int j = 0; j < 4; ++j) cv.h[j] = f2bf(v[j]);
        *(uint2*)((unsigned short*)Out + e) = cv.u;
    } else {
        *(f32x4*)((float*)Out + e) = v;
    }
}

extern "C" void kernel_launch(void* const* d_in, const int* in_sizes, int n_in,
                              void* d_out, int out_size, void* d_ws, size_t ws_size,
                              hipStream_t stream)
{
    const float* x  = (const float*)d_in[0];
    const int*   ei = (const int*)d_in[1];
    const float* gw = (const float*)d_in[2];
    const float* gb = (const float*)d_in[3];
    const float* W1 = (const float*)d_in[4];
    const float* b1 = (const float*)d_in[5];
    const float* W2 = (const float*)d_in[6];
    const float* b2 = (const float*)d_in[7];
    const float* W3 = (const float*)d_in[8];
    const float* b3 = (const float*)d_in[9];
    float* out = (float*)d_out;

    char* ws = (char*)d_ws;
    unsigned short* z   = (unsigned short*)(ws);               // 6,291,456 B
    unsigned short* z1  = (unsigned short*)(ws + 6291456);     // 2,097,152 B
    unsigned short* z2  = (unsigned short*)(ws + 8388608);     // 2,097,152 B
    unsigned short* W1t = (unsigned short*)(ws + 10485760);    // 25,165,824 B
    unsigned short* W2t = (unsigned short*)(ws + 35651584);    // 8,388,608 B
    unsigned short* W3t = (unsigned short*)(ws + 44040192);    // 16,777,216 B
    float* P            = (float*)        (ws + 60817408);     // 33,554,432 B
    int*   c1           = (int*)          (ws + 94371840);
    float* Sg           = (float*)        (ws + 94388224);
    float* dinv         = (float*)        (ws + 94404608);

    // weight transpose+convert (f32 [K][N] -> bf16 [N][K])
    hipLaunchKernelGGL(tcvt, dim3(32, 192), dim3(256), 0, stream, W1, W1t, 6144, 2048);
    hipLaunchKernelGGL(tcvt, dim3(32,  64), dim3(256), 0, stream, W2, W2t, 2048, 2048);
    hipLaunchKernelGGL(tcvt, dim3(64,  64), dim3(256), 0, stream, W3, W3t, 2048, 4096);

    // GCN + z assembly
    hipLaunchKernelGGL(gcn_init,    dim3(16),      dim3(256), 0, stream, c1, Sg);
    hipLaunchKernelGGL(gcn_hist,    dim3(128),     dim3(256), 0, stream, ei + EEDGES, c1);
    hipLaunchKernelGGL(gcn_dinv,    dim3(16),      dim3(256), 0, stream, c1, dinv);
    hipLaunchKernelGGL(gcn_scatter, dim3(128),     dim3(256), 0, stream, ei, ei + EEDGES, x, dinv, Sg);
    hipLaunchKernelGGL(build_z,     dim3(24, 512), dim3(256), 0, stream, x, c1, dinv, Sg, gw, gb, z);

    // L1: z[512,6144] @ W1 -> z1 (relu, bf16). split-K S=8, chunk 768
    hipLaunchKernelGGL(gemm128, dim3(4, 16, 8), dim3(256), 0, stream, z,  W1t, P, 512, 2048, 6144, 768);
    hipLaunchKernelGGL((reduce_ep<true, true>),  dim3(1024), dim3(256), 0, stream, P, b1, (void*)z1, 512 * 2048, 2048, 8);

    // L2: z1[512,2048] @ W2 -> z2 (relu, bf16). S=8, chunk 256
    hipLaunchKernelGGL(gemm128, dim3(4, 16, 8), dim3(256), 0, stream, z1, W2t, P, 512, 2048, 2048, 256);
    hipLaunchKernelGGL((reduce_ep<true, true>),  dim3(1024), dim3(256), 0, stream, P, b2, (void*)z2, 512 * 2048, 2048, 8);

    // L3: z2[512,2048] @ W3 -> out (f32). S=4, chunk 512
    hipLaunchKernelGGL(gemm128, dim3(4, 32, 4), dim3(256), 0, stream, z2, W3t, P, 512, 4096, 2048, 512);
    hipLaunchKernelGGL((reduce_ep<false, false>), dim3(2048), dim3(256), 0, stream, P, b3, (void*)out, 512 * 4096, 4096, 4);
}

// Round 3
// 268.964 us; speedup vs baseline: 1.5316x; 1.0180x over previous
//
#include <hip/hip_runtime.h>

#define NEQ_   4096
#define XDIM_  6144
#define EEDGES 32768

typedef __bf16 bf16x8 __attribute__((ext_vector_type(8)));
typedef float  f32x4  __attribute__((ext_vector_type(4)));

__device__ __forceinline__ unsigned short f2bf(float f) {
    union { float f; unsigned u; } v; v.f = f;
    unsigned r = v.u + 0x7FFFu + ((v.u >> 16) & 1u);   // RNE
    return (unsigned short)(r >> 16);
}

__device__ __forceinline__ void gll16(const void* g, void* l) {
    __builtin_amdgcn_global_load_lds(
        (const __attribute__((address_space(1))) unsigned int*)g,
        (__attribute__((address_space(3))) unsigned int*)l, 16, 0, 0);
}

// ---- GCN prologue (validated rounds 1-2) ----

__global__ void gcn_init(int* __restrict__ c1, float* __restrict__ S) {
    int i = blockIdx.x * 256 + threadIdx.x;
    if (i < NEQ_) { c1[i] = 0; S[i] = 0.f; }
}

__global__ void gcn_hist(const int* __restrict__ dst, int* __restrict__ c1) {
    int e = blockIdx.x * 256 + threadIdx.x;
    if (e < EEDGES) atomicAdd(&c1[dst[e]], 1);
}

__global__ void gcn_dinv(const int* __restrict__ c1, float* __restrict__ dinv) {
    int i = blockIdx.x * 256 + threadIdx.x;
    if (i < NEQ_) dinv[i] = rsqrtf(512.f * (float)c1[i] + 1.f);
}

__global__ void gcn_scatter(const int* __restrict__ src, const int* __restrict__ dst,
                            const float* __restrict__ x, const float* __restrict__ dinv,
                            float* __restrict__ S) {
    int e = blockIdx.x * 256 + threadIdx.x;
    if (e < EEDGES) {
        int s = src[e], d = dst[e];
        float xf = x[(size_t)(s & 511) * XDIM_ + (s >> 9)];
        atomicAdd(&S[d], dinv[s] * xf);
    }
}

__global__ void build_z(const float* __restrict__ x, const int* __restrict__ c1,
                        const float* __restrict__ dinv, const float* __restrict__ S,
                        const float* __restrict__ gw, const float* __restrict__ gb,
                        unsigned short* __restrict__ z) {
    int i = blockIdx.x * 256 + threadIdx.x;  // 0..6143
    int b = blockIdx.y;                      // 0..511
    float xv = x[(size_t)b * XDIM_ + i];
    float v;
    if (i >= NEQ_) {
        v = xv;
    } else {
        float w00 = gw[0], b0 = gb[0];
        if (i >= 8) {
            v = fmaxf(w00 * xv + b0, 0.f);
        } else {
            int n = i * 512 + b;
            float deg = 512.f * (float)c1[n] + 1.f;
            float outv = w00 * (512.f * dinv[n] * S[n] + xv / deg);
            v = fmaxf(outv + b0, 0.f);
        }
    }
    z[(size_t)b * XDIM_ + i] = f2bf(v);
}

// ---- weight transpose+convert: W[K][N] f32 -> Wt[N][K] bf16 ----
// 4 consecutive lanes cover one n at 4 k-chunks of 8 -> each lane writes uint4,
// 4 lanes = one full 64B line of Wt (no write amplification).
// Block: 16 n x 128 k. Grid (N/16, K/128).
__global__ __launch_bounds__(256)
void tcvt(const float* __restrict__ W, unsigned short* __restrict__ Wt, int K, int N) {
    int lane = threadIdx.x & 63, wave = threadIdx.x >> 6;
    int n  = blockIdx.x * 16 + (lane >> 2);
    int kb = (blockIdx.y * 4 + wave) * 32 + (lane & 3) * 8;
    union { unsigned short h[8]; uint4 u; } cv;
    #pragma unroll
    for (int j = 0; j < 8; ++j) cv.h[j] = f2bf(W[(size_t)(kb + j) * N + n]);
    *(uint4*)(Wt + (size_t)n * K + kb) = cv.u;
}

// ---- 64x64-tile MFMA GEMM, BK=64, 4 waves (each 32x32), split-K to P[S][M][N] ----
// LDS panels: addr(m,k) = (k/32)*2048 + m*32 + (k&31) elements; gll16 dst byte addr
// = wave_base + lane*16 exactly (wave-uniform-base constraint honored).
__global__ __launch_bounds__(256)
void gemm64(const unsigned short* __restrict__ A,   // [M][K] bf16
            const unsigned short* __restrict__ Bt,  // [N][K] bf16
            float* __restrict__ P,                  // [S][M][N] f32
            int M, int N, int K, int kChunk)
{
    __shared__ unsigned short As[2 * 64 * 32];   // 8 KB
    __shared__ unsigned short Bs[2 * 64 * 32];   // 8 KB
    const int tid = threadIdx.x, lane = tid & 63, wave = tid >> 6;
    const int m0 = blockIdx.x * 64, n0 = blockIdx.y * 64;
    const int wm = (wave >> 1) * 32, wn = (wave & 1) * 32;
    const int fr = lane & 15, fko = (lane >> 4) * 8;
    const int k0 = blockIdx.z * kChunk, k1 = k0 + kChunk;

    // staging: inst i in {0,1} -> k-half i; thread t -> row t>>2, k-off (t&3)*8
    const int srow = tid >> 2;
    const int sko  = (tid & 3) * 8;
    const size_t aoff = (size_t)(m0 + srow) * K + sko;
    const size_t boff = (size_t)(n0 + srow) * K + sko;
    unsigned short* asl0 = &As[srow * 32 + sko];            // = 8*t elems = 16*t bytes
    unsigned short* asl1 = &As[2048 + srow * 32 + sko];
    unsigned short* bsl0 = &Bs[srow * 32 + sko];
    unsigned short* bsl1 = &Bs[2048 + srow * 32 + sko];

    f32x4 acc[2][2] = {};

    for (int kk = k0; kk < k1; kk += 64) {
        gll16(A + aoff + kk,      asl0);
        gll16(A + aoff + kk + 32, asl1);
        gll16(Bt + boff + kk,      bsl0);
        gll16(Bt + boff + kk + 32, bsl1);
        __syncthreads();

        bf16x8 af[2][2], bf[2][2];
        #pragma unroll
        for (int kh = 0; kh < 2; ++kh)
            #pragma unroll
            for (int t = 0; t < 2; ++t) {
                af[t][kh] = *(const bf16x8*)(&As[kh * 2048 + (wm + t * 16 + fr) * 32 + fko]);
                bf[t][kh] = *(const bf16x8*)(&Bs[kh * 2048 + (wn + t * 16 + fr) * 32 + fko]);
            }
        #pragma unroll
        for (int kh = 0; kh < 2; ++kh)
            #pragma unroll
            for (int mt = 0; mt < 2; ++mt)
                #pragma unroll
                for (int nt = 0; nt < 2; ++nt)
                    acc[mt][nt] = __builtin_amdgcn_mfma_f32_16x16x32_bf16(
                        af[mt][kh], bf[nt][kh], acc[mt][nt], 0, 0, 0);

        __syncthreads();
    }

    float* Pp = P + (size_t)blockIdx.z * M * N;
    const int col = lane & 15, qr = (lane >> 4) * 4;
    #pragma unroll
    for (int mt = 0; mt < 2; ++mt)
    #pragma unroll
    for (int nt = 0; nt < 2; ++nt) {
        int gm = m0 + wm + mt * 16 + qr;
        int gn = n0 + wn + nt * 16 + col;
        #pragma unroll
        for (int r = 0; r < 4; ++r)
            Pp[(size_t)(gm + r) * N + gn] = acc[mt][nt][r];
    }
}

// ---- split-K reduce + bias (+relu) epilogue ----
template<bool RELU, bool OUTBF16>
__global__ __launch_bounds__(256)
void reduce_ep(const float* __restrict__ P, const float* __restrict__ bias,
               void* __restrict__ Out, int MN, int N, int S)
{
    int e = (blockIdx.x * 256 + threadIdx.x) * 4;
    if (e >= MN) return;
    f32x4 v = *(const f32x4*)(P + e);
    for (int s = 1; s < S; ++s) v += *(const f32x4*)(P + (size_t)s * MN + e);
    int nb = e % N;
    f32x4 bv = *(const f32x4*)(bias + nb);
    v += bv;
    if (RELU) {
        #pragma unroll
        for (int j = 0; j < 4; ++j) v[j] = fmaxf(v[j], 0.f);
    }
    if (OUTBF16) {
        union { unsigned short h[4]; uint2 u; } cv;
        #pragma unroll
        for (int j = 0; j < 4; ++j) cv.h[j] = f2bf(v[j]);
        *(uint2*)((unsigned short*)Out + e) = cv.u;
    } else {
        *(f32x4*)((float*)Out + e) = v;
    }
}

extern "C" void kernel_launch(void* const* d_in, const int* in_sizes, int n_in,
                              void* d_out, int out_size, void* d_ws, size_t ws_size,
                              hipStream_t stream)
{
    const float* x  = (const float*)d_in[0];
    const int*   ei = (const int*)d_in[1];
    const float* gw = (const float*)d_in[2];
    const float* gb = (const float*)d_in[3];
    const float* W1 = (const float*)d_in[4];
    const float* b1 = (const float*)d_in[5];
    const float* W2 = (const float*)d_in[6];
    const float* b2 = (const float*)d_in[7];
    const float* W3 = (const float*)d_in[8];
    const float* b3 = (const float*)d_in[9];
    float* out = (float*)d_out;

    char* ws = (char*)d_ws;
    unsigned short* z   = (unsigned short*)(ws);               // 6,291,456 B
    unsigned short* z1  = (unsigned short*)(ws + 6291456);     // 2,097,152 B
    unsigned short* z2  = (unsigned short*)(ws + 8388608);     // 2,097,152 B
    unsigned short* W1t = (unsigned short*)(ws + 10485760);    // 25,165,824 B
    unsigned short* W2t = (unsigned short*)(ws + 35651584);    // 8,388,608 B
    unsigned short* W3t = (unsigned short*)(ws + 44040192);    // 16,777,216 B
    float* P            = (float*)        (ws + 60817408);     // 33,554,432 B
    int*   c1           = (int*)          (ws + 94371840);
    float* Sg           = (float*)        (ws + 94388224);
    float* dinv         = (float*)        (ws + 94404608);

    // weight transpose+convert (f32 [K][N] -> bf16 [N][K])
    hipLaunchKernelGGL(tcvt, dim3(128, 48), dim3(256), 0, stream, W1, W1t, 6144, 2048);
    hipLaunchKernelGGL(tcvt, dim3(128, 16), dim3(256), 0, stream, W2, W2t, 2048, 2048);
    hipLaunchKernelGGL(tcvt, dim3(256, 16), dim3(256), 0, stream, W3, W3t, 2048, 4096);

    // GCN + z assembly
    hipLaunchKernelGGL(gcn_init,    dim3(16),      dim3(256), 0, stream, c1, Sg);
    hipLaunchKernelGGL(gcn_hist,    dim3(128),     dim3(256), 0, stream, ei + EEDGES, c1);
    hipLaunchKernelGGL(gcn_dinv,    dim3(16),      dim3(256), 0, stream, c1, dinv);
    hipLaunchKernelGGL(gcn_scatter, dim3(128),     dim3(256), 0, stream, ei, ei + EEDGES, x, dinv, Sg);
    hipLaunchKernelGGL(build_z,     dim3(24, 512), dim3(256), 0, stream, x, c1, dinv, Sg, gw, gb, z);

    // L1: z[512,6144] @ W1 -> z1 (relu, bf16). S=3, chunk 2048 (32 iters), 768 blocks
    hipLaunchKernelGGL(gemm64, dim3(8, 32, 3), dim3(256), 0, stream, z,  W1t, P, 512, 2048, 6144, 2048);
    hipLaunchKernelGGL((reduce_ep<true, true>),  dim3(1024), dim3(256), 0, stream, P, b1, (void*)z1, 512 * 2048, 2048, 3);

    // L2: z1[512,2048] @ W2 -> z2 (relu, bf16). S=2, chunk 1024 (16 iters), 512 blocks
    hipLaunchKernelGGL(gemm64, dim3(8, 32, 2), dim3(256), 0, stream, z1, W2t, P, 512, 2048, 2048, 1024);
    hipLaunchKernelGGL((reduce_ep<true, true>),  dim3(1024), dim3(256), 0, stream, P, b2, (void*)z2, 512 * 2048, 2048, 2);

    // L3: z2[512,2048] @ W3 -> out (f32). S=2, chunk 1024 (16 iters), 1024 blocks
    hipLaunchKernelGGL(gemm64, dim3(8, 64, 2), dim3(256), 0, stream, z2, W3t, P, 512, 4096, 2048, 1024);
    hipLaunchKernelGGL((reduce_ep<false, false>), dim3(2048), dim3(256), 0, stream, P, b3, (void*)out, 512 * 4096, 4096, 2);
}